// Round 13
// baseline (63.337 us; speedup 1.0000x reference)
//
#include <hip/hip_runtime.h>

// Output: (224, 2, 257, 600) f32.  plane pl = b*56 + slot, slot = 2*p + s,
// pairs from triu_indices(8, k=1). c_ch[slot] = source channel.
__device__ __constant__ int c_ch[56] = {
    0,1, 0,2, 0,3, 0,4, 0,5, 0,6, 0,7,
    1,2, 1,3, 1,4, 1,5, 1,6, 1,7,
    2,3, 2,4, 2,5, 2,6, 2,7,
    3,4, 3,5, 3,6, 3,7,
    4,5, 4,6, 4,7,
    5,6, 5,7,
    6,7
};

// Clique-ordered pair walk: groups {0123},{01x45},{23x45},{4567},{01x67},{23x67}
// -> any two adjacent groups span only 6 channels (3.7 MB < 4 MB L2/XCD).
__device__ __constant__ int c_seq[28] = {
     0,  1,  2,  7,  8, 13,    // G1: pairs inside {0,1,2,3}
     3,  4,  9, 10,            // G2: {0,1} x {4,5}
    14, 15, 18, 19,            // G3: {2,3} x {4,5}
    22, 23, 24, 25, 26, 27,    // G6: pairs inside {4,5,6,7}
     5,  6, 11, 12,            // G4: {0,1} x {6,7}
    16, 17, 20, 21             // G5: {2,3} x {6,7}
};

typedef float f32x4 __attribute__((ext_vector_type(4)));

#define PLANE4 38550   // 257*600/4 float4 per plane (plane = 616800 B, mod 128 = 96)
#define GRIDX  19      // chunks per plane
#define TPP    (GRIDX * 256)   // 4864 threads per plane; 4864*16 B % 128 == 0
#define EPT    8               // float4 per thread

// R12 structure with PLAIN stores (A/B on store type in the L2-fit regime):
// full-line aligned bursts write-allocate with no RFO and drain via L2's
// write-back machinery (fill kernel: 6.9 TB/s); read set 3.7 MB stays hot
// under LRU since store lines are never re-referenced.
__global__ void gather_pairs_kernel(const f32x4* __restrict__ in,
                                    f32x4* __restrict__ out) {
    unsigned w     = blockIdx.x;
    unsigned b     = w & 7u;          // batch == XCD
    unsigned local = w >> 3;          // 0..1063
    unsigned seq   = local / 19u;     // sequence position 0..55 (magic-mul)
    unsigned chunk = local - seq * 19u;     // 0..18
    unsigned slot  = 2u * (unsigned)c_seq[seq >> 1] + (seq & 1u);
    unsigned pl    = b * 56u + slot;
    unsigned ch    = (unsigned)c_ch[slot];  // wave-uniform scalar load

    const f32x4* __restrict__ src = in  + (size_t)((b << 3) + ch) * PLANE4;
    f32x4*       __restrict__ dst = out + (size_t)pl * PLANE4;

    // plane base mod 128 cycles with pl&3: 0,96,64,32. Peel leading float4s
    // so bulk accesses are 128-B line-aligned (loads AND stores).
    int off  = ((pl & 3) * 96) & 127;
    int peel = ((128 - off) & 127) >> 4;   // 0, 2, 4, or 6 float4s

    int t = chunk * 256 + threadIdx.x;     // 0..4863
    if (t < peel) {
        dst[t] = src[t];
    }

    // 8-deep MLP: all 8 loads issued before any store waits on them.
    int  idx[EPT];
    f32x4 v[EPT];
#pragma unroll
    for (int k = 0; k < EPT; ++k) idx[k] = peel + t + k * TPP;
    bool p7 = idx[EPT - 1] < PLANE4;

#pragma unroll
    for (int k = 0; k < EPT - 1; ++k) v[k] = src[idx[k]];
    if (p7) v[EPT - 1] = src[idx[EPT - 1]];

#pragma unroll
    for (int k = 0; k < EPT - 1; ++k) dst[idx[k]] = v[k];
    if (p7) dst[idx[EPT - 1]] = v[EPT - 1];
}

extern "C" void kernel_launch(void* const* d_in, const int* in_sizes, int n_in,
                              void* d_out, int out_size, void* d_ws, size_t ws_size,
                              hipStream_t stream) {
    const f32x4* in  = (const f32x4*)d_in[0];
    f32x4*       out = (f32x4*)d_out;
    dim3 block(256, 1, 1);
    dim3 grid(8 * 56 * GRIDX, 1, 1);   // 8512 blocks, batch-affine, clique order
    gather_pairs_kernel<<<grid, block, 0, stream>>>(in, out);
}

// Round 14
// 51.992 us; speedup vs baseline: 1.2182x; 1.2182x over previous
//
#include <hip/hip_runtime.h>

// Output: (224, 2, 257, 600) f32.  plane pl = b*56 + slot, slot = 2*p + s,
// pairs from triu_indices(8, k=1). c_ch[slot] = source channel.
__device__ __constant__ int c_ch[56] = {
    0,1, 0,2, 0,3, 0,4, 0,5, 0,6, 0,7,
    1,2, 1,3, 1,4, 1,5, 1,6, 1,7,
    2,3, 2,4, 2,5, 2,6, 2,7,
    3,4, 3,5, 3,6, 3,7,
    4,5, 4,6, 4,7,
    5,6, 5,7,
    6,7
};

// Clique-ordered pair walk: groups {0123},{01x45},{23x45},{4567},{01x67},{23x67}
// -> any two adjacent groups span only 6 channels (3.7 MB < 4 MB L2/XCD).
__device__ __constant__ int c_seq[28] = {
     0,  1,  2,  7,  8, 13,    // G1: pairs inside {0,1,2,3}
     3,  4,  9, 10,            // G2: {0,1} x {4,5}
    14, 15, 18, 19,            // G3: {2,3} x {4,5}
    22, 23, 24, 25, 26, 27,    // G6: pairs inside {4,5,6,7}
     5,  6, 11, 12,            // G4: {0,1} x {6,7}
    16, 17, 20, 21             // G5: {2,3} x {6,7}
};

typedef float f32x4 __attribute__((ext_vector_type(4)));

#define PLANE4 38550   // 257*600/4 float4 per plane (plane = 616800 B, mod 128 = 96)
#define GRIDX  19      // chunks per plane
#define TPP    (GRIDX * 256)   // 4864 threads per plane; 4864*16 B % 128 == 0
#define EPT    8               // float4 per thread

// Final structure (R12): XCD-batch affinity + clique-ordered plane walk
// (read set 3.7 MB < 4 MB L2/XCD) + peel alignment + 8-deep MLP + NT stores.
__global__ void gather_pairs_kernel(const f32x4* __restrict__ in,
                                    f32x4* __restrict__ out) {
    unsigned w     = blockIdx.x;
    unsigned b     = w & 7u;          // batch == XCD
    unsigned local = w >> 3;          // 0..1063
    unsigned seq   = local / 19u;     // sequence position 0..55 (magic-mul)
    unsigned chunk = local - seq * 19u;     // 0..18
    unsigned slot  = 2u * (unsigned)c_seq[seq >> 1] + (seq & 1u);
    unsigned pl    = b * 56u + slot;
    unsigned ch    = (unsigned)c_ch[slot];  // wave-uniform scalar load

    const f32x4* __restrict__ src = in  + (size_t)((b << 3) + ch) * PLANE4;
    f32x4*       __restrict__ dst = out + (size_t)pl * PLANE4;

    // plane base mod 128 cycles with pl&3: 0,96,64,32. Peel leading float4s
    // so bulk accesses are 128-B line-aligned (loads AND stores).
    int off  = ((pl & 3) * 96) & 127;
    int peel = ((128 - off) & 127) >> 4;   // 0, 2, 4, or 6 float4s

    int t = chunk * 256 + threadIdx.x;     // 0..4863
    if (t < peel) {
        f32x4 v = src[t];
        __builtin_nontemporal_store(v, &dst[t]);
    }

    // 8-deep MLP: all 8 loads issued before any store waits on them.
    int  idx[EPT];
    f32x4 v[EPT];
#pragma unroll
    for (int k = 0; k < EPT; ++k) idx[k] = peel + t + k * TPP;
    bool p7 = idx[EPT - 1] < PLANE4;

#pragma unroll
    for (int k = 0; k < EPT - 1; ++k) v[k] = src[idx[k]];
    if (p7) v[EPT - 1] = src[idx[EPT - 1]];

#pragma unroll
    for (int k = 0; k < EPT - 1; ++k)
        __builtin_nontemporal_store(v[k], &dst[idx[k]]);
    if (p7) __builtin_nontemporal_store(v[EPT - 1], &dst[idx[EPT - 1]]);
}

extern "C" void kernel_launch(void* const* d_in, const int* in_sizes, int n_in,
                              void* d_out, int out_size, void* d_ws, size_t ws_size,
                              hipStream_t stream) {
    const f32x4* in  = (const f32x4*)d_in[0];
    f32x4*       out = (f32x4*)d_out;
    dim3 block(256, 1, 1);
    dim3 grid(8 * 56 * GRIDX, 1, 1);   // 8512 blocks, batch-affine, clique order
    gather_pairs_kernel<<<grid, block, 0, stream>>>(in, out);
}